// Round 1
// baseline (632.849 us; speedup 1.0000x reference)
//
#include <hip/hip_runtime.h>
#include <math.h>

// Workspace layout (floats):
//   dinv  : N          (deg accumulated, then rsqrt in place)
//   h0    : 16*N       (x @ W1)
//   h1    : 16*N       (layer-1 scatter accumulator -> relu'd hidden)
//   t2    : 16*N       (h1 @ W2)
//   h2    : 16*N       (layer-2 scatter accumulator)
//   g     : 16*G       (graph pool accumulator)
// Total = 65*N + 16*G floats ~= 26.1 MB for N=100k, G=1000.

__global__ void k_init(float* dinv, float* h1, float* h2, float* g, int N, int G) {
    int i = blockIdx.x * blockDim.x + threadIdx.x;
    int n16 = N * 16;
    if (i < n16) { h1[i] = 0.0f; h2[i] = 0.0f; }
    if (i < N)      dinv[i] = 1.0f;          // self-loop contribution to degree
    if (i < G * 16) g[i]    = 0.0f;
}

__global__ void k_deg(const int* __restrict__ col, float* deg, int E) {
    int e = blockIdx.x * blockDim.x + threadIdx.x;
    if (e < E) atomicAdd(&deg[col[e]], 1.0f);
}

__global__ void k_rsqrt(float* deg_to_dinv, int N) {
    int v = blockIdx.x * blockDim.x + threadIdx.x;
    if (v < N) deg_to_dinv[v] = rsqrtf(deg_to_dinv[v]);
}

// h0[v][k] = sum_c x[v][c] * W1[c][k]   (W1 is 3x16 row-major)
__global__ void k_xw1(const float* __restrict__ x, const float* __restrict__ W1,
                      float* __restrict__ h0, int N) {
    int t = blockIdx.x * blockDim.x + threadIdx.x;
    if (t >= N * 16) return;
    int v = t >> 4, k = t & 15;
    float x0 = x[v * 3 + 0], x1 = x[v * 3 + 1], x2 = x[v * 3 + 2];
    h0[t] = x0 * W1[k] + x1 * W1[16 + k] + x2 * W1[32 + k];
}

// dst[col[e]][k] += dinv[row[e]]*dinv[col[e]] * src[row[e]][k]
// 16 threads per edge; lane k handles feature k (coalesced src row read).
__global__ void k_scatter(const int* __restrict__ row, const int* __restrict__ col,
                          const float* __restrict__ dinv,
                          const float* __restrict__ src, float* dst, int E) {
    int t = blockIdx.x * blockDim.x + threadIdx.x;
    if (t >= E * 16) return;
    int e = t >> 4, k = t & 15;
    int r = row[e], c = col[e];
    float w = dinv[r] * dinv[c];
    atomicAdd(&dst[c * 16 + k], w * src[r * 16 + k]);
}

// h1[v][k] = relu(h1_acc[v][k] + dinv[v]^2 * h0[v][k] + b1[k])
__global__ void k_finish1(const float* __restrict__ dinv, const float* __restrict__ h0,
                          const float* __restrict__ b1, float* h1, int N) {
    int t = blockIdx.x * blockDim.x + threadIdx.x;
    if (t >= N * 16) return;
    int v = t >> 4, k = t & 15;
    float d = dinv[v];
    float val = h1[t] + d * d * h0[t] + b1[k];
    h1[t] = fmaxf(val, 0.0f);
}

// t2[v][k] = sum_j h1[v][j] * W2[j][k]   (W2 16x16 row-major, staged in LDS)
__global__ void k_hw2(const float* __restrict__ h1, const float* __restrict__ W2,
                      float* __restrict__ t2, int N) {
    __shared__ float sW[256];
    if (threadIdx.x < 256) sW[threadIdx.x] = W2[threadIdx.x];
    __syncthreads();
    int t = blockIdx.x * blockDim.x + threadIdx.x;
    if (t >= N * 16) return;
    int v = t >> 4, k = t & 15;
    const float* hr = h1 + v * 16;
    float acc = 0.0f;
#pragma unroll
    for (int j = 0; j < 16; ++j) acc += hr[j] * sW[j * 16 + k];
    t2[t] = acc;
}

// val = h2_acc[v][k] + dinv[v]^2 * t2[v][k] + b2[k];  g[batch[v]][k] += val
__global__ void k_finish2_pool(const float* __restrict__ dinv, const float* __restrict__ t2,
                               const float* __restrict__ b2, const float* __restrict__ h2,
                               const int* __restrict__ batch, float* g, int N) {
    int t = blockIdx.x * blockDim.x + threadIdx.x;
    if (t >= N * 16) return;
    int v = t >> 4, k = t & 15;
    float d = dinv[v];
    float val = h2[t] + d * d * t2[t] + b2[k];
    atomicAdd(&g[batch[v] * 16 + k], val);
}

// logits = g @ Wl + bl (16x7), then log_softmax over 7. One thread per graph.
__global__ void k_head(const float* __restrict__ g, const float* __restrict__ Wl,
                       const float* __restrict__ bl, float* __restrict__ out, int G) {
    int gi = blockIdx.x * blockDim.x + threadIdx.x;
    if (gi >= G) return;
    float gv[16];
#pragma unroll
    for (int k = 0; k < 16; ++k) gv[k] = g[gi * 16 + k];
    float lo[7];
    float mx = -1e30f;
#pragma unroll
    for (int j = 0; j < 7; ++j) {
        float a = bl[j];
#pragma unroll
        for (int k = 0; k < 16; ++k) a += gv[k] * Wl[k * 7 + j];
        lo[j] = a;
        mx = fmaxf(mx, a);
    }
    float s = 0.0f;
#pragma unroll
    for (int j = 0; j < 7; ++j) s += expf(lo[j] - mx);
    float lse = mx + logf(s);
#pragma unroll
    for (int j = 0; j < 7; ++j) out[gi * 7 + j] = lo[j] - lse;
}

extern "C" void kernel_launch(void* const* d_in, const int* in_sizes, int n_in,
                              void* d_out, int out_size, void* d_ws, size_t ws_size,
                              hipStream_t stream) {
    const float* x    = (const float*)d_in[0];
    const int*   ei   = (const int*)d_in[1];   // [2, E]: row = ei[0:E), col = ei[E:2E)
    // d_in[2] = edge_attr, unused by the reference
    const int*   batch = (const int*)d_in[3];
    const float* W1 = (const float*)d_in[4];
    const float* b1 = (const float*)d_in[5];
    const float* W2 = (const float*)d_in[6];
    const float* b2 = (const float*)d_in[7];
    const float* Wl = (const float*)d_in[8];
    const float* bl = (const float*)d_in[9];
    float* out = (float*)d_out;

    const int N = in_sizes[0] / 3;
    const int E = in_sizes[1] / 2;
    const int G = out_size / 7;

    const int* row = ei;
    const int* col = ei + E;

    float* ws   = (float*)d_ws;
    float* dinv = ws;                 // N
    float* h0   = dinv + N;           // 16N
    float* h1   = h0 + 16 * N;        // 16N
    float* t2   = h1 + 16 * N;        // 16N
    float* h2   = t2 + 16 * N;        // 16N
    float* g    = h2 + 16 * N;        // 16G

    const int TB = 256;
    const int n16 = N * 16;

    k_init<<<(n16 + TB - 1) / TB, TB, 0, stream>>>(dinv, h1, h2, g, N, G);
    k_deg<<<(E + TB - 1) / TB, TB, 0, stream>>>(col, dinv, E);
    k_rsqrt<<<(N + TB - 1) / TB, TB, 0, stream>>>(dinv, N);
    k_xw1<<<(n16 + TB - 1) / TB, TB, 0, stream>>>(x, W1, h0, N);
    k_scatter<<<(E * 16 + TB - 1) / TB, TB, 0, stream>>>(row, col, dinv, h0, h1, E);
    k_finish1<<<(n16 + TB - 1) / TB, TB, 0, stream>>>(dinv, h0, b1, h1, N);
    k_hw2<<<(n16 + TB - 1) / TB, TB, 0, stream>>>(h1, W2, t2, N);
    k_scatter<<<(E * 16 + TB - 1) / TB, TB, 0, stream>>>(row, col, dinv, t2, h2, E);
    k_finish2_pool<<<(n16 + TB - 1) / TB, TB, 0, stream>>>(dinv, t2, b2, h2, batch, g, N);
    k_head<<<(G + TB - 1) / TB, TB, 0, stream>>>(g, Wl, bl, out, G);
}